// Round 1
// baseline (980.505 us; speedup 1.0000x reference)
//
#include <hip/hip_runtime.h>
#include <math.h>

#define D 64

// out[i] = 0.25 * (tanh(g0)*3) * x[i]
__global__ void init_out_kernel(float* __restrict__ out, const float* __restrict__ x,
                                const float* __restrict__ gammas, int n) {
    float coef = 0.25f * (tanhf(gammas[0]) * 3.0f);
    int i = blockIdx.x * blockDim.x + threadIdx.x;
    int stride = gridDim.x * blockDim.x;
    for (; i < n; i += stride) {
        out[i] = coef * x[i];
    }
}

// acc[row[e]*64 + lane] += w[e] * z[col[e]*64 + lane]; one wave (64 lanes) per edge
__global__ void spmm_kernel(const int* __restrict__ row, const int* __restrict__ col,
                            const float* __restrict__ w, const float* __restrict__ z,
                            float* __restrict__ acc, int n_edges) {
    int gid = blockIdx.x * blockDim.x + threadIdx.x;
    int wave = gid >> 6;
    int lane = threadIdx.x & 63;
    int n_waves = (gridDim.x * blockDim.x) >> 6;
    for (int e = wave; e < n_edges; e += n_waves) {
        int r = row[e];
        int c = col[e];
        float wt = w[e];
        float v = wt * z[(long)c * D + lane];
        atomicAdd(&acc[(long)r * D + lane], v);
    }
}

// z = cA*Az + cB*zp1 + cC*zp2 ; dst = z ; out += (0.25 * prod_{j<=l} tanh(g[j])*3) * z
// dst may alias Az (same-index elementwise).
__global__ void combine_kernel(float* __restrict__ dst, const float* __restrict__ Az,
                               const float* __restrict__ zp1, const float* __restrict__ zp2,
                               float cA, float cB, float cC,
                               float* __restrict__ out, const float* __restrict__ gammas,
                               int l, int n) {
    float coef = 0.25f;
    for (int j = 0; j <= l; ++j) coef *= tanhf(gammas[j]) * 3.0f;
    int i = blockIdx.x * blockDim.x + threadIdx.x;
    int stride = gridDim.x * blockDim.x;
    for (; i < n; i += stride) {
        float zv = cA * Az[i] + cB * zp1[i] + cC * zp2[i];
        dst[i] = zv;
        out[i] += coef * zv;
    }
}

extern "C" void kernel_launch(void* const* d_in, const int* in_sizes, int n_in,
                              void* d_out, int out_size, void* d_ws, size_t ws_size,
                              hipStream_t stream) {
    const float* x      = (const float*)d_in[0];
    const int*   ei     = (const int*)d_in[1];   // [2, E] row-major: row then col
    const float* w      = (const float*)d_in[2];
    const float* gammas = (const float*)d_in[3]; // [L+1]

    const int E = in_sizes[1] / 2;
    const int N = in_sizes[0] / D;
    const long NF = (long)N * D;

    float* out = (float*)d_out;
    float* B1 = (float*)d_ws;        // z1
    float* B2 = B1 + NF;             // z2
    float* B3 = B2 + NF;             // Az2 / z3

    const int* row = ei;
    const int* col = ei + E;

    const double a = 1.0, b = 1.0;

    const int blk = 256;
    const int egrid = (int)((NF + blk - 1) / blk) < 4096 ? (int)((NF + blk - 1) / blk) : 4096;
    const int spmm_grid = (E + 3) / 4;  // 4 waves per block, 1 edge per wave

    // out = 0.25*coef0*x
    init_out_kernel<<<egrid, blk, 0, stream>>>(out, x, gammas, (int)NF);

    // ---- l = 1: z1 = ((a-b)/2) z0 + ((a+b+2)/2) A z0
    {
        double cA = (a + b + 2.0) / 2.0;
        double cB = (a - b) / 2.0;
        hipMemsetAsync(B1, 0, NF * sizeof(float), stream);
        spmm_kernel<<<spmm_grid, blk, 0, stream>>>(row, col, w, x, B1, E);
        combine_kernel<<<egrid, blk, 0, stream>>>(B1, B1, x, x,
                                                  (float)cA, (float)cB, 0.0f,
                                                  out, gammas, 1, (int)NF);
    }

    // ---- l = 2, 3: z_l = (c1 z_{l-1} + c2 A z_{l-1} - c3 z_{l-2}) / c0
    const float* zp1 = B1;
    const float* zp2 = x;
    float* zbufs[2] = { B2, B3 };
    for (int l = 2; l <= 3; ++l) {
        double c0 = 2.0 * l * (l + a + b) * (2.0 * l + a + b - 2.0);
        double c1 = (2.0 * l + a + b - 1.0) * (a * a - b * b);
        double c2 = (2.0 * l + a + b - 1.0) * (2.0 * l + a + b) * (2.0 * l + a + b - 2.0);
        double c3 = 2.0 * (l + a - 1.0) * (l + b - 1.0) * (2.0 * l + a + b);
        float* dst = zbufs[l - 2];
        hipMemsetAsync(dst, 0, NF * sizeof(float), stream);
        spmm_kernel<<<spmm_grid, blk, 0, stream>>>(row, col, w, zp1, dst, E);
        combine_kernel<<<egrid, blk, 0, stream>>>(dst, dst, zp1, zp2,
                                                  (float)(c2 / c0), (float)(c1 / c0), (float)(-c3 / c0),
                                                  out, gammas, l, (int)NF);
        zp2 = zp1;
        zp1 = dst;
    }
}

// Round 2
// 752.020 us; speedup vs baseline: 1.3038x; 1.3038x over previous
//
#include <hip/hip_runtime.h>
#include <math.h>

#define D 64

// ---------------- CSR build ----------------

__global__ void count_kernel(const int* __restrict__ row, int* __restrict__ counts, int E) {
    int i = blockIdx.x * blockDim.x + threadIdx.x;
    int stride = gridDim.x * blockDim.x;
    for (; i < E; i += stride) atomicAdd(&counts[row[i]], 1);
}

// Single-workgroup exclusive scan: counts[0..N) -> row_ptr[0..N]
__global__ void scan_kernel(const int* __restrict__ counts, int* __restrict__ row_ptr, int N) {
    __shared__ int sums[1024];
    const int T = 1024;
    int t = threadIdx.x;
    int chunk = (N + T - 1) / T;
    int lo = t * chunk;
    int hi = min(N, lo + chunk);
    int s = 0;
    for (int i = lo; i < hi; ++i) s += counts[i];
    sums[t] = s;
    __syncthreads();
    // Hillis-Steele inclusive scan over 1024 entries
    for (int off = 1; off < T; off <<= 1) {
        int v = (t >= off) ? sums[t - off] : 0;
        __syncthreads();
        sums[t] += v;
        __syncthreads();
    }
    int run = (t == 0) ? 0 : sums[t - 1];  // exclusive offset for this chunk
    for (int i = lo; i < hi; ++i) {
        row_ptr[i] = run;
        run += counts[i];
    }
    if (t == T - 1) row_ptr[N] = sums[T - 1];
}

// Scatter edges into CSR order; cursor[] must be zeroed first.
__global__ void scatter_kernel(const int* __restrict__ row, const int* __restrict__ col,
                               const float* __restrict__ w, const int* __restrict__ row_ptr,
                               int* __restrict__ cursor, int2* __restrict__ edges, int E) {
    int i = blockIdx.x * blockDim.x + threadIdx.x;
    int stride = gridDim.x * blockDim.x;
    for (; i < E; i += stride) {
        int r = row[i];
        int pos = row_ptr[r] + atomicAdd(&cursor[r], 1);
        edges[pos] = make_int2(col[i], __float_as_int(w[i]));
    }
}

// ---------------- fused SpMM + recurrence + output accumulation ----------------
// One wave per row; lane = feature. acc = (A zp1)[row].
// z = cA*acc + cB*zp1[row] + cC*zp2[row]
// if zdst: zdst[row] = z
// out[row] = first ? 0.25*(coef_{l-1? no: coef0}*x + coef_l*z) : out[row] + 0.25*coef_l*z
__global__ void spmm_combine_kernel(const int* __restrict__ row_ptr,
                                    const int2* __restrict__ edges,
                                    const float* __restrict__ zp1,
                                    const float* __restrict__ zp2,
                                    float* __restrict__ zdst,
                                    float* __restrict__ out,
                                    const float* __restrict__ gammas,
                                    float cA, float cB, float cC,
                                    int l, int first, int N) {
    int gid = blockIdx.x * blockDim.x + threadIdx.x;
    int r = gid >> 6;          // one wave per row
    int lane = threadIdx.x & 63;
    if (r >= N) return;

    // cumulative coefficients (cheap, wave-uniform)
    float coef = 0.25f;
    float coef0 = 0.25f * (tanhf(gammas[0]) * 3.0f);
    for (int j = 0; j <= l; ++j) coef *= tanhf(gammas[j]) * 3.0f;

    int s = row_ptr[r];
    int e = row_ptr[r + 1];
    float acc = 0.0f;
    for (int k = s; k < e; ++k) {
        int2 ed = edges[k];
        float wt = __int_as_float(ed.y);
        acc += wt * zp1[(long)ed.x * D + lane];
    }
    long idx = (long)r * D + lane;
    float z = cA * acc + cB * zp1[idx] + cC * zp2[idx];
    if (zdst) zdst[idx] = z;
    if (first) out[idx] = coef0 * zp1[idx] + coef * z;   // zp1 == x when first
    else out[idx] += coef * z;
}

extern "C" void kernel_launch(void* const* d_in, const int* in_sizes, int n_in,
                              void* d_out, int out_size, void* d_ws, size_t ws_size,
                              hipStream_t stream) {
    const float* x      = (const float*)d_in[0];
    const int*   ei     = (const int*)d_in[1];   // [2, E]: row then col
    const float* w      = (const float*)d_in[2];
    const float* gammas = (const float*)d_in[3]; // [L+1]

    const int E = in_sizes[1] / 2;
    const int N = in_sizes[0] / D;
    const long NF = (long)N * D;

    float* out = (float*)d_out;

    // ws layout
    float* z1 = (float*)d_ws;
    float* z2 = z1 + NF;
    int* counts  = (int*)(z2 + NF);
    int* row_ptr = counts + N;
    size_t edge_off = (size_t)(2 * NF) + N + ((N + 2) & ~1);  // 8B-align edges
    int2* edges = (int2*)((float*)d_ws + edge_off);

    const int* row = ei;
    const int* col = ei + E;

    const double a = 1.0, b = 1.0;
    const int blk = 256;

    // ---- build CSR (per launch; inputs constant but ws is re-poisoned) ----
    hipMemsetAsync(counts, 0, (size_t)N * sizeof(int), stream);
    count_kernel<<<2048, blk, 0, stream>>>(row, counts, E);
    scan_kernel<<<1, 1024, 0, stream>>>(counts, row_ptr, N);
    hipMemsetAsync(counts, 0, (size_t)N * sizeof(int), stream);  // reuse as cursor
    scatter_kernel<<<2048, blk, 0, stream>>>(row, col, w, row_ptr, counts, edges, E);

    const int sgrid = (N + 3) / 4;  // 4 waves (rows) per 256-thread block

    // ---- l = 1: z1 = ((a-b)/2) x + ((a+b+2)/2) A x ; out = 0.25*(coef0*x + coef1*z1)
    {
        float cA = (float)((a + b + 2.0) / 2.0);
        float cB = (float)((a - b) / 2.0);
        spmm_combine_kernel<<<sgrid, blk, 0, stream>>>(row_ptr, edges, x, x, z1, out, gammas,
                                                       cA, cB, 0.0f, 1, 1, N);
    }

    // ---- l = 2,3
    const float* zp1 = z1;
    const float* zp2 = x;
    for (int l = 2; l <= 3; ++l) {
        double c0 = 2.0 * l * (l + a + b) * (2.0 * l + a + b - 2.0);
        double c1 = (2.0 * l + a + b - 1.0) * (a * a - b * b);
        double c2 = (2.0 * l + a + b - 1.0) * (2.0 * l + a + b) * (2.0 * l + a + b - 2.0);
        double c3 = 2.0 * (l + a - 1.0) * (l + b - 1.0) * (2.0 * l + a + b);
        float* zdst = (l == 2) ? z2 : nullptr;  // z3 never re-read
        spmm_combine_kernel<<<sgrid, blk, 0, stream>>>(row_ptr, edges, zp1, zp2, zdst, out, gammas,
                                                       (float)(c2 / c0), (float)(c1 / c0),
                                                       (float)(-c3 / c0), l, 0, N);
        zp2 = zp1;
        zp1 = zdst ? zdst : nullptr;
    }
}

// Round 3
// 500.455 us; speedup vs baseline: 1.9592x; 1.5027x over previous
//
#include <hip/hip_runtime.h>
#include <math.h>

#define D 64

// ---------------- CSR build ----------------

__global__ void count_kernel(const int* __restrict__ row, int* __restrict__ counts, int E) {
    int i = blockIdx.x * blockDim.x + threadIdx.x;
    int stride = gridDim.x * blockDim.x;
    for (; i < E; i += stride) atomicAdd(&counts[row[i]], 1);
}

// --- hierarchical exclusive scan of counts[0..N) into row_ptr[0..N] ---
// 1024 elements per block, 256 threads x 4 elems.

__global__ void scan_reduce_kernel(const int* __restrict__ counts, int* __restrict__ block_sums, int N) {
    __shared__ int lds[256];
    int b = blockIdx.x, t = threadIdx.x;
    int base = b * 1024;
    int s = 0;
#pragma unroll
    for (int k = 0; k < 4; ++k) {
        int i = base + k * 256 + t;
        if (i < N) s += counts[i];
    }
    lds[t] = s;
    __syncthreads();
    for (int off = 128; off > 0; off >>= 1) {
        if (t < off) lds[t] += lds[t + off];
        __syncthreads();
    }
    if (t == 0) block_sums[b] = lds[0];
}

// single block, B <= 1024 block sums -> exclusive offsets
__global__ void scan_blocksums_kernel(const int* __restrict__ block_sums,
                                      int* __restrict__ block_offs, int B) {
    __shared__ int lds[1024];
    int t = threadIdx.x;
    lds[t] = (t < B) ? block_sums[t] : 0;
    __syncthreads();
    for (int off = 1; off < 1024; off <<= 1) {
        int v = (t >= off) ? lds[t - off] : 0;
        __syncthreads();
        lds[t] += v;
        __syncthreads();
    }
    if (t < B) block_offs[t] = (t == 0) ? 0 : lds[t - 1];
}

__global__ void scan_final_kernel(const int* __restrict__ counts, const int* __restrict__ block_offs,
                                  int* __restrict__ row_ptr, int N, int E) {
    __shared__ int lds[256];
    int b = blockIdx.x, t = threadIdx.x;
    int base = b * 1024 + t * 4;
    int c[4];
    int s = 0;
#pragma unroll
    for (int k = 0; k < 4; ++k) {
        int i = base + k;
        c[k] = (i < N) ? counts[i] : 0;
        s += c[k];
    }
    lds[t] = s;
    __syncthreads();
    for (int off = 1; off < 256; off <<= 1) {
        int u = (t >= off) ? lds[t - off] : 0;
        __syncthreads();
        lds[t] += u;
        __syncthreads();
    }
    int excl = (t == 0) ? 0 : lds[t - 1];
    int run = block_offs[b] + excl;
#pragma unroll
    for (int k = 0; k < 4; ++k) {
        int i = base + k;
        if (i < N) row_ptr[i] = run;
        run += c[k];
    }
    if (b == 0 && t == 0) row_ptr[N] = E;
}

// Scatter edges into CSR order; cursor[] must be zeroed first.
__global__ void scatter_kernel(const int* __restrict__ row, const int* __restrict__ col,
                               const float* __restrict__ w, const int* __restrict__ row_ptr,
                               int* __restrict__ cursor, int2* __restrict__ edges, int E) {
    int i = blockIdx.x * blockDim.x + threadIdx.x;
    int stride = gridDim.x * blockDim.x;
    for (; i < E; i += stride) {
        int r = row[i];
        int pos = row_ptr[r] + atomicAdd(&cursor[r], 1);
        edges[pos] = make_int2(col[i], __float_as_int(w[i]));
    }
}

// ---------------- fused SpMM + recurrence + output accumulation ----------------
// One wave per row; lane = feature.
__global__ void spmm_combine_kernel(const int* __restrict__ row_ptr,
                                    const int2* __restrict__ edges,
                                    const float* __restrict__ zp1,
                                    const float* __restrict__ zp2,
                                    float* __restrict__ zdst,
                                    float* __restrict__ out,
                                    const float* __restrict__ gammas,
                                    float cA, float cB, float cC,
                                    int l, int first, int N) {
    int gid = blockIdx.x * blockDim.x + threadIdx.x;
    int r = gid >> 6;
    int lane = threadIdx.x & 63;
    if (r >= N) return;

    float coef = 0.25f;
    float coef0 = 0.25f * (tanhf(gammas[0]) * 3.0f);
    for (int j = 0; j <= l; ++j) coef *= tanhf(gammas[j]) * 3.0f;

    int s = row_ptr[r];
    int e = row_ptr[r + 1];
    float acc = 0.0f;
    int k = s;
    for (; k + 1 < e; k += 2) {   // unroll-by-2: two gathers in flight
        int2 e0 = edges[k];
        int2 e1 = edges[k + 1];
        float v0 = zp1[(long)e0.x * D + lane];
        float v1 = zp1[(long)e1.x * D + lane];
        acc += __int_as_float(e0.y) * v0;
        acc += __int_as_float(e1.y) * v1;
    }
    if (k < e) {
        int2 e0 = edges[k];
        acc += __int_as_float(e0.y) * zp1[(long)e0.x * D + lane];
    }

    long idx = (long)r * D + lane;
    float z = cA * acc + cB * zp1[idx] + cC * zp2[idx];
    if (zdst) zdst[idx] = z;
    if (first) out[idx] = coef0 * zp1[idx] + coef * z;   // zp1 == x when first
    else out[idx] += coef * z;
}

extern "C" void kernel_launch(void* const* d_in, const int* in_sizes, int n_in,
                              void* d_out, int out_size, void* d_ws, size_t ws_size,
                              hipStream_t stream) {
    const float* x      = (const float*)d_in[0];
    const int*   ei     = (const int*)d_in[1];   // [2, E]: row then col
    const float* w      = (const float*)d_in[2];
    const float* gammas = (const float*)d_in[3]; // [L+1]

    const int E = in_sizes[1] / 2;
    const int N = in_sizes[0] / D;
    const long NF = (long)N * D;

    float* out = (float*)d_out;

    // ws layout
    float* z1 = (float*)d_ws;
    float* z2 = z1 + NF;
    int* counts     = (int*)(z2 + NF);
    int* row_ptr    = counts + N;          // N+1 ints
    int* block_sums = row_ptr + N + 1;     // 1024
    int* block_offs = block_sums + 1024;   // 1024
    size_t off_ints = (size_t)(2 * NF) + N + (N + 1) + 2048;
    off_ints = (off_ints + 1) & ~(size_t)1;  // 8B-align
    int2* edges = (int2*)((int*)d_ws + off_ints);

    const int* row = ei;
    const int* col = ei + E;

    const double a = 1.0, b = 1.0;
    const int blk = 256;

    // ---- build CSR ----
    hipMemsetAsync(counts, 0, (size_t)N * sizeof(int), stream);
    count_kernel<<<2048, blk, 0, stream>>>(row, counts, E);
    int B = (N + 1023) / 1024;
    scan_reduce_kernel<<<B, 256, 0, stream>>>(counts, block_sums, N);
    scan_blocksums_kernel<<<1, 1024, 0, stream>>>(block_sums, block_offs, B);
    scan_final_kernel<<<B, 256, 0, stream>>>(counts, block_offs, row_ptr, N, E);
    hipMemsetAsync(counts, 0, (size_t)N * sizeof(int), stream);  // reuse as cursor
    scatter_kernel<<<2048, blk, 0, stream>>>(row, col, w, row_ptr, counts, edges, E);

    const int sgrid = (N + 3) / 4;  // 4 waves (rows) per 256-thread block

    // ---- l = 1 ----
    {
        float cA = (float)((a + b + 2.0) / 2.0);
        float cB = (float)((a - b) / 2.0);
        spmm_combine_kernel<<<sgrid, blk, 0, stream>>>(row_ptr, edges, x, x, z1, out, gammas,
                                                       cA, cB, 0.0f, 1, 1, N);
    }

    // ---- l = 2,3 ----
    const float* zp1 = z1;
    const float* zp2 = x;
    for (int l = 2; l <= 3; ++l) {
        double c0 = 2.0 * l * (l + a + b) * (2.0 * l + a + b - 2.0);
        double c1 = (2.0 * l + a + b - 1.0) * (a * a - b * b);
        double c2 = (2.0 * l + a + b - 1.0) * (2.0 * l + a + b) * (2.0 * l + a + b - 2.0);
        double c3 = 2.0 * (l + a - 1.0) * (l + b - 1.0) * (2.0 * l + a + b);
        float* zdst = (l == 2) ? z2 : nullptr;  // z3 never re-read
        spmm_combine_kernel<<<sgrid, blk, 0, stream>>>(row_ptr, edges, zp1, zp2, zdst, out, gammas,
                                                       (float)(c2 / c0), (float)(c1 / c0),
                                                       (float)(-c3 / c0), l, 0, N);
        zp2 = zp1;
        zp1 = zdst ? zdst : nullptr;
    }
}

// Round 4
// 413.490 us; speedup vs baseline: 2.3713x; 1.2103x over previous
//
#include <hip/hip_runtime.h>
#include <math.h>

#define D 64

// ---------------- CSR build ----------------

__global__ void count_kernel(const int* __restrict__ row, int* __restrict__ counts, int E) {
    int i = blockIdx.x * blockDim.x + threadIdx.x;
    int stride = gridDim.x * blockDim.x;
    for (; i < E; i += stride) atomicAdd(&counts[row[i]], 1);
}

// --- hierarchical exclusive scan of counts[0..N) into row_ptr[0..N] ---

__global__ void scan_reduce_kernel(const int* __restrict__ counts, int* __restrict__ block_sums, int N) {
    __shared__ int lds[256];
    int b = blockIdx.x, t = threadIdx.x;
    int base = b * 1024;
    int s = 0;
#pragma unroll
    for (int k = 0; k < 4; ++k) {
        int i = base + k * 256 + t;
        if (i < N) s += counts[i];
    }
    lds[t] = s;
    __syncthreads();
    for (int off = 128; off > 0; off >>= 1) {
        if (t < off) lds[t] += lds[t + off];
        __syncthreads();
    }
    if (t == 0) block_sums[b] = lds[0];
}

__global__ void scan_blocksums_kernel(const int* __restrict__ block_sums,
                                      int* __restrict__ block_offs, int B) {
    __shared__ int lds[1024];
    int t = threadIdx.x;
    lds[t] = (t < B) ? block_sums[t] : 0;
    __syncthreads();
    for (int off = 1; off < 1024; off <<= 1) {
        int v = (t >= off) ? lds[t - off] : 0;
        __syncthreads();
        lds[t] += v;
        __syncthreads();
    }
    if (t < B) block_offs[t] = (t == 0) ? 0 : lds[t - 1];
}

__global__ void scan_final_kernel(const int* __restrict__ counts, const int* __restrict__ block_offs,
                                  int* __restrict__ row_ptr, int N, int E) {
    __shared__ int lds[256];
    int b = blockIdx.x, t = threadIdx.x;
    int base = b * 1024 + t * 4;
    int c[4];
    int s = 0;
#pragma unroll
    for (int k = 0; k < 4; ++k) {
        int i = base + k;
        c[k] = (i < N) ? counts[i] : 0;
        s += c[k];
    }
    lds[t] = s;
    __syncthreads();
    for (int off = 1; off < 256; off <<= 1) {
        int u = (t >= off) ? lds[t - off] : 0;
        __syncthreads();
        lds[t] += u;
        __syncthreads();
    }
    int excl = (t == 0) ? 0 : lds[t - 1];
    int run = block_offs[b] + excl;
#pragma unroll
    for (int k = 0; k < 4; ++k) {
        int i = base + k;
        if (i < N) row_ptr[i] = run;
        run += c[k];
    }
    if (b == 0 && t == 0) row_ptr[N] = E;
}

// Scatter edges into CSR order; cursor[] must be zeroed first.
__global__ void scatter_kernel(const int* __restrict__ row, const int* __restrict__ col,
                               const float* __restrict__ w, const int* __restrict__ row_ptr,
                               int* __restrict__ cursor, int2* __restrict__ edges, int E) {
    int i = blockIdx.x * blockDim.x + threadIdx.x;
    int stride = gridDim.x * blockDim.x;
    for (; i < E; i += stride) {
        int r = row[i];
        int pos = row_ptr[r] + atomicAdd(&cursor[r], 1);
        edges[pos] = make_int2(col[i], __float_as_int(w[i]));
    }
}

// ---------------- fused SpMM + recurrence + output accumulation ----------------
// One wave per row; lane = feature. Edge loop chunked 8/4/1 so up to 8
// independent 256B gathers are in flight per wave (latency hiding).
__global__ void spmm_combine_kernel(const int* __restrict__ row_ptr,
                                    const int2* __restrict__ edges,
                                    const float* __restrict__ zp1,
                                    const float* __restrict__ zp2,
                                    float* __restrict__ zdst,
                                    float* __restrict__ out,
                                    const float* __restrict__ gammas,
                                    float cA, float cB, float cC,
                                    int l, int first, int N) {
    int gid = blockIdx.x * blockDim.x + threadIdx.x;
    int r = gid >> 6;
    int lane = threadIdx.x & 63;
    if (r >= N) return;

    float coef = 0.25f;
    float coef0 = 0.25f * (tanhf(gammas[0]) * 3.0f);
    for (int j = 0; j <= l; ++j) coef *= tanhf(gammas[j]) * 3.0f;

    int k = row_ptr[r];
    int e = row_ptr[r + 1];
    float acc = 0.0f;

    for (; k + 8 <= e; k += 8) {
        int2 ed[8];
#pragma unroll
        for (int j = 0; j < 8; ++j) ed[j] = edges[k + j];
        float v[8];
#pragma unroll
        for (int j = 0; j < 8; ++j) v[j] = zp1[(long)ed[j].x * D + lane];
#pragma unroll
        for (int j = 0; j < 8; ++j) acc += __int_as_float(ed[j].y) * v[j];
    }
    if (k + 4 <= e) {
        int2 ed[4];
#pragma unroll
        for (int j = 0; j < 4; ++j) ed[j] = edges[k + j];
        float v[4];
#pragma unroll
        for (int j = 0; j < 4; ++j) v[j] = zp1[(long)ed[j].x * D + lane];
#pragma unroll
        for (int j = 0; j < 4; ++j) acc += __int_as_float(ed[j].y) * v[j];
        k += 4;
    }
    if (k < e) {
        int2 ed[3];
        float v[3];
        int m = e - k;
#pragma unroll
        for (int j = 0; j < 3; ++j) if (j < m) ed[j] = edges[k + j];
#pragma unroll
        for (int j = 0; j < 3; ++j) if (j < m) v[j] = zp1[(long)ed[j].x * D + lane];
#pragma unroll
        for (int j = 0; j < 3; ++j) if (j < m) acc += __int_as_float(ed[j].y) * v[j];
    }

    long idx = (long)r * D + lane;
    float z = cA * acc + cB * zp1[idx] + cC * zp2[idx];
    if (zdst) zdst[idx] = z;
    if (first) out[idx] = coef0 * zp1[idx] + coef * z;   // zp1 == x when first
    else out[idx] += coef * z;
}

extern "C" void kernel_launch(void* const* d_in, const int* in_sizes, int n_in,
                              void* d_out, int out_size, void* d_ws, size_t ws_size,
                              hipStream_t stream) {
    const float* x      = (const float*)d_in[0];
    const int*   ei     = (const int*)d_in[1];   // [2, E]: row then col
    const float* w      = (const float*)d_in[2];
    const float* gammas = (const float*)d_in[3]; // [L+1]

    const int E = in_sizes[1] / 2;
    const int N = in_sizes[0] / D;
    const long NF = (long)N * D;

    float* out = (float*)d_out;

    // ws layout
    float* z1 = (float*)d_ws;
    float* z2 = z1 + NF;
    int* counts     = (int*)(z2 + NF);
    int* row_ptr    = counts + N;          // N+1 ints
    int* block_sums = row_ptr + N + 1;     // 1024
    int* block_offs = block_sums + 1024;   // 1024
    size_t off_ints = (size_t)(2 * NF) + N + (N + 1) + 2048;
    off_ints = (off_ints + 1) & ~(size_t)1;  // 8B-align
    int2* edges = (int2*)((int*)d_ws + off_ints);

    const int* row = ei;
    const int* col = ei + E;

    const double a = 1.0, b = 1.0;
    const int blk = 256;

    // ---- build CSR ----
    hipMemsetAsync(counts, 0, (size_t)N * sizeof(int), stream);
    count_kernel<<<2048, blk, 0, stream>>>(row, counts, E);
    int B = (N + 1023) / 1024;
    scan_reduce_kernel<<<B, 256, 0, stream>>>(counts, block_sums, N);
    scan_blocksums_kernel<<<1, 1024, 0, stream>>>(block_sums, block_offs, B);
    scan_final_kernel<<<B, 256, 0, stream>>>(counts, block_offs, row_ptr, N, E);
    hipMemsetAsync(counts, 0, (size_t)N * sizeof(int), stream);  // reuse as cursor
    scatter_kernel<<<2048, blk, 0, stream>>>(row, col, w, row_ptr, counts, edges, E);

    const int sgrid = (N + 3) / 4;  // 4 waves (rows) per 256-thread block

    // ---- l = 1 ----
    {
        float cA = (float)((a + b + 2.0) / 2.0);
        float cB = (float)((a - b) / 2.0);
        spmm_combine_kernel<<<sgrid, blk, 0, stream>>>(row_ptr, edges, x, x, z1, out, gammas,
                                                       cA, cB, 0.0f, 1, 1, N);
    }

    // ---- l = 2,3 ----
    const float* zp1 = z1;
    const float* zp2 = x;
    for (int l = 2; l <= 3; ++l) {
        double c0 = 2.0 * l * (l + a + b) * (2.0 * l + a + b - 2.0);
        double c1 = (2.0 * l + a + b - 1.0) * (a * a - b * b);
        double c2 = (2.0 * l + a + b - 1.0) * (2.0 * l + a + b) * (2.0 * l + a + b - 2.0);
        double c3 = 2.0 * (l + a - 1.0) * (l + b - 1.0) * (2.0 * l + a + b);
        float* zdst = (l == 2) ? z2 : nullptr;  // z3 never re-read
        spmm_combine_kernel<<<sgrid, blk, 0, stream>>>(row_ptr, edges, zp1, zp2, zdst, out, gammas,
                                                       (float)(c2 / c0), (float)(c1 / c0),
                                                       (float)(-c3 / c0), l, 0, N);
        zp2 = zp1;
        zp1 = zdst ? zdst : nullptr;
    }
}